// Round 5
// baseline (12745.450 us; speedup 1.0000x reference)
//
#include <hip/hip_runtime.h>
#include <math.h>

#define LN   720
#define NBIN 361
#define CCH  128
#define NPAIRS 8128   // 128*127/2
#define PB     2032   // pairs blocks per batch (4 pairs/block)

// ---------------------------------------------------------------- tables
__global__ void k_twiddle(double* __restrict__ ct, double* __restrict__ st) {
  int m = blockIdx.x * 256 + threadIdx.x;
  if (m < LN) {
    double a = 6.2831853071795864769252867665590057684 * (double)m / 720.0;
    ct[m] = cos(a);
    st[m] = sin(a);
  }
}

__global__ void k_dctmat(float* __restrict__ D) {
  int idx = blockIdx.x * 256 + threadIdx.x;
  if (idx < LN * LN) {
    int k = idx / LN, l = idx - k * LN;
    double ang = 3.1415926535897932384626433832795028842 * (double)((2 * l + 1) * k) / 1440.0;
    double v = cos(ang) * sqrt(2.0 / 720.0);
    if (k == 0) v *= 0.70710678118654752440084436210485;
    D[idx] = (float)v;
  }
}

// ---------------------------------------------------------------- rfft (fp64 backbone) -> fp32-quantized nrf
// Replicates: rf = rfft(x) rounded to complex64; nrf = rf / max(|rf|,1e-8) in fp32 ops.
__global__ __launch_bounds__(256) void k_rfft(const float* __restrict__ x,
                                              const double* __restrict__ ctg,
                                              const double* __restrict__ stg,
                                              float* __restrict__ nR,
                                              float* __restrict__ nI) {
  __shared__ double sd[LN];
  __shared__ double cts[LN], sts[LN];
  int b = blockIdx.x >> 7, c = blockIdx.x & 127;
  int t = threadIdx.x;
  for (int m = t; m < LN; m += 256) { cts[m] = ctg[m]; sts[m] = stg[m]; }
  for (int l = t; l < LN; l += 256) sd[l] = (double)x[(b * LN + l) * CCH + c];
  __syncthreads();
  size_t gbase = (size_t)blockIdx.x * NBIN;
  for (int k = t; k < NBIN; k += 256) {
    double re = 0.0, im = 0.0;
    int idx = 0;
    for (int l = 0; l < LN; l++) {
      double s = sd[l];
      re += s * cts[idx];
      im -= s * sts[idx];
      idx += k; if (idx >= LN) idx -= LN;
    }
    float reF = (float)re, imF = (float)im;        // complex64 quantization of rf
    float mag = hypotf(reF, imF);                   // np.abs(complex64)
    float d = fmaxf(mag, 1e-8f);
    nR[gbase + k] = __fdiv_rn(reF, d);              // complex64 / float32, per-component fp32
    nI[gbase + k] = __fdiv_rn(imF, d);
  }
}

// ---------------------------------------------------------------- phase correlation
// cross computed in strict fp32 (complex64 semantics), Hermitian inverse in fp64,
// pc rounded to fp32 BEFORE max/argmax; ties -> lowest index (np/jax argmax).
// Pair symmetry: pc[j,i,nt] with nt=(720-n)%720 is bit-equal to pc[i,j,n].
__global__ __launch_bounds__(256) void k_pc(const float* __restrict__ nR,
                                            const float* __restrict__ nI,
                                            const double* __restrict__ ctg,
                                            const double* __restrict__ stg,
                                            float* __restrict__ Mv, int* __restrict__ Mi) {
  __shared__ double cs[LN], sn[LN];
  __shared__ double cRe[4][NBIN], cIm[4][NBIN];
  int bid = blockIdx.x;
  int b = bid / PB;
  int p = (bid - b * PB) * 4 + (threadIdx.x >> 6);   // pair index, wave-uniform
  int t = threadIdx.x;
  int lane = t & 63, w = t >> 6;

  for (int v = t; v < LN; v += 256) { cs[v] = ctg[v]; sn[v] = stg[v]; }

  // decode i<j from triangular pair index (wave-uniform scalar loop)
  int i = 0, rem = p;
  while (rem >= 127 - i) { rem -= 127 - i; i++; }
  int j = i + 1 + rem;

  // cross[k] = nrf_i[k] * conj(nrf_j[k]) in strict fp32, upcast to fp64
  {
    size_t ib = ((size_t)(b << 7) + i) * NBIN;
    size_t jb = ((size_t)(b << 7) + j) * NBIN;
    for (int k = lane; k < NBIN; k += 64) {
      float aR = nR[ib + k], aI = nI[ib + k];
      float bR = nR[jb + k], bI = nI[jb + k];
      float xr = __fadd_rn(__fmul_rn(aR, bR), __fmul_rn(aI, bI));
      float xi = __fsub_rn(__fmul_rn(aI, bR), __fmul_rn(aR, bI));
      cRe[w][k] = (double)xr;
      cIm[w][k] = (double)xi;
    }
  }
  __syncthreads();

  double dc = cRe[w][0];
  double ny = cRe[w][360];

  float bv1 = -3.0e38f; int bx1 = 0;   // pair (i,j)
  float bv2 = -3.0e38f; int bx2 = 0;   // pair (j,i)
#pragma unroll 1
  for (int q = 0; q < 12; q++) {
    int n = lane + (q << 6);
    if (n < LN) {
      double acc = 0.0;
      int idx = n;
#pragma unroll 4
      for (int k = 1; k < 360; k++) {
        acc = fma(cRe[w][k], cs[idx], acc);
        acc = fma(-cIm[w][k], sn[idx], acc);
        idx += n; if (idx >= LN) idx -= LN;
      }
      double pcn = (dc + ((n & 1) ? -ny : ny) + 2.0 * acc) * (1.0 / 720.0);
      float pf = (float)pcn;                       // fp32 quantization of pc
      if (pf > bv1 || (pf == bv1 && n < bx1)) { bv1 = pf; bx1 = n; }
      int nt = (n == 0) ? 0 : (LN - n);
      if (pf > bv2 || (pf == bv2 && nt < bx2)) { bv2 = pf; bx2 = nt; }
    }
  }
  for (int off = 32; off >= 1; off >>= 1) {
    float ov = __shfl_down(bv1, off); int oi = __shfl_down(bx1, off);
    if (ov > bv1 || (ov == bv1 && oi < bx1)) { bv1 = ov; bx1 = oi; }
    float ov2 = __shfl_down(bv2, off); int oi2 = __shfl_down(bx2, off);
    if (ov2 > bv2 || (ov2 == bv2 && oi2 < bx2)) { bv2 = ov2; bx2 = oi2; }
  }
  if (lane == 0) {
    int o1 = (((b << 7) + i) << 7) + j;
    int o2 = (((b << 7) + j) << 7) + i;
    Mv[o1] = bv1; Mi[o1] = bx1;
    Mv[o2] = bv2; Mi[o2] = bx2;
  }
}

// ---------------------------------------------------------------- top-8 (fp32, literal selection)
__global__ __launch_bounds__(64) void k_topk(const float* __restrict__ Mv, const int* __restrict__ Mi,
                                             int* __restrict__ lid, int* __restrict__ shf,
                                             float* __restrict__ rv) {
  int b = blockIdx.x >> 7, r = blockIdx.x & 127;
  if (threadIdx.x != 0) return;
  float sval[128]; int ssh[128];
  int base = (((b << 7) + r) << 7);
  for (int j = 0; j < 128; j++) {
    if (j == r) { sval[j] = -3.0e38f; ssh[j] = 0; continue; }  // masked diag (max_ii-2 never wins)
    float mvv = Mv[base + j]; int mii = Mi[base + j];
    sval[j] = mvv;
    ssh[j] = (mii > 360) ? (mii - 720) : mii;    // np: where(idx > L//2, idx-L, idx)
  }
  for (int k = 0; k < 8; k++) {
    float best = -3.0e38f; int bj = 0;
    for (int j = 0; j < 128; j++)
      if (sval[j] > best) { best = sval[j]; bj = j; }  // strict '>': lowest index on ties
    int o = (((b << 7) + r) << 3) + k;
    lid[o] = bj; rv[o] = best; shf[o] = ssh[bj];
    sval[bj] = -3.0e38f;
  }
}

// ---------------------------------------------------------------- gather + DCT + bands (fp32, literal)
__global__ __launch_bounds__(256) void k_out(const float* __restrict__ x,
                                             const float* __restrict__ D,
                                             const int* __restrict__ lid,
                                             const int* __restrict__ shf,
                                             const float* __restrict__ rv,
                                             float* __restrict__ out) {
  __shared__ float xe[9 * LN];
  __shared__ float X[9 * LN];
  __shared__ int s_lid[8], s_shf[8];
  __shared__ float s_r[8];
  int b = blockIdx.x >> 7, c = blockIdx.x & 127;
  int t = threadIdx.x;
  if (t < 8) {
    int q = (((b << 7) + c) << 3) + t;
    s_lid[t] = lid[q]; s_shf[t] = shf[q]; s_r[t] = rv[q];
  }
  __syncthreads();

  for (int l = t; l < LN; l += 256) xe[l] = x[(b * LN + l) * CCH + c];
  for (int p = 1; p <= 8; p++) {
    float r = s_r[p - 1];
    if (fabsf(r) < 0.1f) {
      for (int l = t; l < LN; l += 256) xe[p * LN + l] = x[(b * LN + l) * CCH + c];
    } else {
      float sg = (r < 0.f) ? -1.f : 1.f;
      int ld = s_lid[p - 1], sh = s_shf[p - 1];
      for (int l = t; l < LN; l += 256) {
        int tt = l - sh; tt = tt < 0 ? 0 : (tt > 719 ? 719 : tt);
        xe[p * LN + l] = sg * x[(b * LN + tt) * CCH + ld];
      }
    }
  }
  __syncthreads();

  for (int task = t; task < 9 * LN; task += 256) {
    int p = task / LN, k = task - p * LN;
    const float* Dk = D + (size_t)k * LN;
    const float* xp = xe + p * LN;
    float acc = 0.f;
    for (int l = 0; l < LN; l++) acc += Dk[l] * xp[l];
    X[task] = acc;
  }
  __syncthreads();

  size_t slab = (size_t)((b << 7) + c) * (LN * 36);
  for (int id = t; id < LN * 36; id += 256) {
    int n = id / 36;
    int remv = id - n * 36;
    int p = remv >> 2;
    int f = remv & 3;
    float acc = 0.f;
    const float* Xp = X + p * LN;
    int k0 = f * 180;
    for (int k = 0; k < 180; k++)
      acc += Xp[k0 + k] * D[(size_t)(k0 + k) * LN + n];
    out[slab + id] = acc;
  }
}

// ---------------------------------------------------------------- launch
extern "C" void kernel_launch(void* const* d_in, const int* in_sizes, int n_in,
                              void* d_out, int out_size, void* d_ws, size_t ws_size,
                              hipStream_t stream) {
  const float* x = (const float*)d_in[0];
  float* out = (float*)d_out;

  char* ws = (char*)d_ws;
  double* ct  = (double*)ws;                      // 720
  double* st  = ct + 720;                         // 720
  float*  nRr = (float*)(st + 720);               // 1024*361
  float*  nIr = nRr + 1024 * NBIN;                // 1024*361
  float*  Mv  = nIr + 1024 * NBIN;                // 8*128*128
  float*  rv  = Mv + 8 * 128 * 128;               // 8*128*8
  float*  D   = rv + 8 * 128 * 8;                 // 720*720
  int*    Mi  = (int*)(D + 720 * 720);            // 8*128*128
  int*    lid = Mi + 8 * 128 * 128;               // 8*128*8
  int*    shf = lid + 8 * 128 * 8;                // 8*128*8

  k_twiddle<<<3, 256, 0, stream>>>(ct, st);
  k_dctmat<<<(720 * 720 + 255) / 256, 256, 0, stream>>>(D);
  k_rfft<<<8 * 128, 256, 0, stream>>>(x, ct, st, nRr, nIr);
  k_pc<<<8 * PB, 256, 0, stream>>>(nRr, nIr, ct, st, Mv, Mi);
  k_topk<<<8 * 128, 64, 0, stream>>>(Mv, Mi, lid, shf, rv);
  k_out<<<8 * 128, 256, 0, stream>>>(x, D, lid, shf, rv, out);
}

// Round 6
// 3782.327 us; speedup vs baseline: 3.3697x; 3.3697x over previous
//
#include <hip/hip_runtime.h>
#include <math.h>

#define LN   720
#define NBIN 361
#define CCH  128
#define NPAIRS 8128   // 128*127/2
#define NP     12     // pairs per k_pc block
#define NPG    678    // ceil(8128/12)

// ---------------------------------------------------------------- tables
__global__ void k_twiddle(double* __restrict__ ct, double* __restrict__ st) {
  int m = blockIdx.x * 256 + threadIdx.x;
  if (m < LN) {
    double a = 6.2831853071795864769252867665590057684 * (double)m / 720.0;
    ct[m] = cos(a);
    st[m] = sin(a);
  }
}

// Cm[k*720+n] = ct[(k*n)%720], Sm likewise — bit-identical to the LDS gather values.
__global__ void k_wmat(const double* __restrict__ ct, const double* __restrict__ st,
                       double* __restrict__ Cm, double* __restrict__ Sm) {
  int idx = blockIdx.x * 256 + threadIdx.x;
  if (idx < NBIN * LN) {
    int k = idx / LN, n = idx - k * LN;
    int r = (int)(((long long)k * n) % LN);
    Cm[idx] = ct[r];
    Sm[idx] = st[r];
  }
}

__global__ void k_ptab(int2* __restrict__ ptab) {
  int p = blockIdx.x * 256 + threadIdx.x;
  if (p < NPAIRS) {
    int i = 0, rem = p;
    while (rem >= 127 - i) { rem -= 127 - i; i++; }
    ptab[p] = make_int2(i, i + 1 + rem);
  }
}

__global__ void k_dctmat(float* __restrict__ D) {
  int idx = blockIdx.x * 256 + threadIdx.x;
  if (idx < LN * LN) {
    int k = idx / LN, l = idx - k * LN;
    double ang = 3.1415926535897932384626433832795028842 * (double)((2 * l + 1) * k) / 1440.0;
    double v = cos(ang) * sqrt(2.0 / 720.0);
    if (k == 0) v *= 0.70710678118654752440084436210485;
    D[idx] = (float)v;
  }
}

// ---------------------------------------------------------------- rfft (fp64 backbone) -> fp32-quantized nrf
// Same math/order as round 5; LDS trig tables padded (idx + idx>>4) to break bank conflicts.
__global__ __launch_bounds__(256) void k_rfft(const float* __restrict__ x,
                                              const double* __restrict__ ctg,
                                              const double* __restrict__ stg,
                                              float* __restrict__ nR,
                                              float* __restrict__ nI) {
  __shared__ double sd[LN];
  __shared__ double ctsP[768], stsP[768];
  int b = blockIdx.x >> 7, c = blockIdx.x & 127;
  int t = threadIdx.x;
  for (int m = t; m < LN; m += 256) {
    int a = m + (m >> 4);
    ctsP[a] = ctg[m]; stsP[a] = stg[m];
  }
  for (int l = t; l < LN; l += 256) sd[l] = (double)x[(b * LN + l) * CCH + c];
  __syncthreads();
  size_t gbase = (size_t)blockIdx.x * NBIN;
  for (int k = t; k < NBIN; k += 256) {
    double re = 0.0, im = 0.0;
    int idx = 0;
    for (int l = 0; l < LN; l++) {
      double s = sd[l];
      int a = idx + (idx >> 4);
      re += s * ctsP[a];
      im -= s * stsP[a];
      idx += k; if (idx >= LN) idx -= LN;
    }
    float reF = (float)re, imF = (float)im;        // complex64 quantization of rf
    float mag = hypotf(reF, imF);
    float d = fmaxf(mag, 1e-8f);
    nR[gbase + k] = __fdiv_rn(reF, d);
    nI[gbase + k] = __fdiv_rn(imF, d);
  }
}

// ---------------------------------------------------------------- phase correlation (GEMM-style)
// cross in strict fp32 (frozen invariant), irfft backbone fp64 with k-ascending
// fma(Re*C) ; fma(-Im*S) order — bit-identical to round 5. pc fp32-quantized
// before max/argmax; ties -> lowest index. Symmetry: (j,i) uses index (720-n)%720.
__global__ __launch_bounds__(256, 2) void k_pc(const float* __restrict__ nR,
                                               const float* __restrict__ nI,
                                               const double* __restrict__ Cm,
                                               const double* __restrict__ Sm,
                                               const int2* __restrict__ ptab,
                                               float* __restrict__ Mv, int* __restrict__ Mi) {
  __shared__ double2 cC[NP][NBIN];       // .x = Re, .y = Im
  __shared__ int2 spair[NP];
  __shared__ float wv[4][NP][2];
  __shared__ int   wi[4][NP][2];
  int b = blockIdx.x / NPG;
  int pg = blockIdx.x - b * NPG;
  int pbase = pg * NP;
  int np = NPAIRS - pbase; if (np > NP) np = NP;
  int t = threadIdx.x;
  if (t < np) spair[t] = ptab[pbase + t];
  __syncthreads();

  // stage cross (strict fp32, upcast to fp64)
  for (int v = t; v < np * NBIN; v += 256) {
    int p = v / NBIN, k = v - p * NBIN;
    int i = spair[p].x, j = spair[p].y;
    size_t ib = ((size_t)(b << 7) + i) * NBIN + k;
    size_t jb = ((size_t)(b << 7) + j) * NBIN + k;
    float aR = nR[ib], aI = nI[ib];
    float bR = nR[jb], bI = nI[jb];
    float xr = __fadd_rn(__fmul_rn(aR, bR), __fmul_rn(aI, bI));
    float xi = __fsub_rn(__fmul_rn(aI, bR), __fmul_rn(aR, bI));
    cC[p][k] = make_double2((double)xr, (double)xi);
  }
  __syncthreads();

  // accumulate: thread t owns n = t, t+256, t+512(<720)
  int n0 = t, n1 = t + 256, n2 = t + 512;
  bool has2 = (t < 208);
  double acc0[NP], acc1[NP], acc2[NP];
#pragma unroll
  for (int p = 0; p < NP; p++) { acc0[p] = 0.0; acc1[p] = 0.0; acc2[p] = 0.0; }

#pragma unroll 2
  for (int k = 1; k < 360; k++) {
    const double* Cr = Cm + (size_t)k * LN;
    const double* Sr = Sm + (size_t)k * LN;
    double C0 = Cr[n0], C1 = Cr[n1];
    double S0 = Sr[n0], S1 = Sr[n1];
    double C2 = has2 ? Cr[n2] : 0.0;
    double S2 = has2 ? Sr[n2] : 0.0;
#pragma unroll
    for (int p = 0; p < NP; p++) {
      double2 cx = cC[p][k];
      double cr = cx.x, ci = cx.y;
      acc0[p] = fma(cr, C0, acc0[p]); acc0[p] = fma(-ci, S0, acc0[p]);
      acc1[p] = fma(cr, C1, acc1[p]); acc1[p] = fma(-ci, S1, acc1[p]);
      acc2[p] = fma(cr, C2, acc2[p]); acc2[p] = fma(-ci, S2, acc2[p]);
    }
  }

  // epilogue: fp32 quantize + argmax (both directions)
  float b1v[NP], b2v[NP]; int b1i[NP], b2i[NP];
#pragma unroll
  for (int p = 0; p < NP; p++) { b1v[p] = -3.0e38f; b2v[p] = -3.0e38f; b1i[p] = 0x7fffffff; b2i[p] = 0x7fffffff; }
#pragma unroll
  for (int q = 0; q < 3; q++) {
    int n = t + (q << 8);
    if (n < LN) {
#pragma unroll
      for (int p = 0; p < NP; p++) {
        double acc = (q == 0) ? acc0[p] : (q == 1) ? acc1[p] : acc2[p];
        double dc = cC[p][0].x, ny = cC[p][360].x;
        double pcn = (dc + ((n & 1) ? -ny : ny) + 2.0 * acc) * (1.0 / 720.0);
        float pf = (float)pcn;                       // fp32 quantization of pc
        if (pf > b1v[p] || (pf == b1v[p] && n < b1i[p])) { b1v[p] = pf; b1i[p] = n; }
        int nt = (n == 0) ? 0 : (LN - n);
        if (pf > b2v[p] || (pf == b2v[p] && nt < b2i[p])) { b2v[p] = pf; b2i[p] = nt; }
      }
    }
  }
  int lane = t & 63, w = t >> 6;
#pragma unroll
  for (int p = 0; p < NP; p++) {
    for (int off = 32; off >= 1; off >>= 1) {
      float ov = __shfl_down(b1v[p], off); int oi = __shfl_down(b1i[p], off);
      if (ov > b1v[p] || (ov == b1v[p] && oi < b1i[p])) { b1v[p] = ov; b1i[p] = oi; }
      float ov2 = __shfl_down(b2v[p], off); int oi2 = __shfl_down(b2i[p], off);
      if (ov2 > b2v[p] || (ov2 == b2v[p] && oi2 < b2i[p])) { b2v[p] = ov2; b2i[p] = oi2; }
    }
    if (lane == 0) {
      wv[w][p][0] = b1v[p]; wi[w][p][0] = b1i[p];
      wv[w][p][1] = b2v[p]; wi[w][p][1] = b2i[p];
    }
  }
  __syncthreads();
  if (t < NP * 2) {
    int p = t >> 1, d = t & 1;
    if (p < np) {
      float bv = wv[0][p][d]; int bi = wi[0][p][d];
      for (int ww = 1; ww < 4; ww++) {
        float ov = wv[ww][p][d]; int oi = wi[ww][p][d];
        if (ov > bv || (ov == bv && oi < bi)) { bv = ov; bi = oi; }
      }
      int i = spair[p].x, j = spair[p].y;
      int o = d ? ((((b << 7) + j) << 7) + i) : ((((b << 7) + i) << 7) + j);
      Mv[o] = bv; Mi[o] = bi;
    }
  }
}

// ---------------------------------------------------------------- top-8 (fp32, literal selection)
__global__ __launch_bounds__(64) void k_topk(const float* __restrict__ Mv, const int* __restrict__ Mi,
                                             int* __restrict__ lid, int* __restrict__ shf,
                                             float* __restrict__ rv) {
  int b = blockIdx.x >> 7, r = blockIdx.x & 127;
  if (threadIdx.x != 0) return;
  float sval[128]; int ssh[128];
  int base = (((b << 7) + r) << 7);
  for (int j = 0; j < 128; j++) {
    if (j == r) { sval[j] = -3.0e38f; ssh[j] = 0; continue; }
    float mvv = Mv[base + j]; int mii = Mi[base + j];
    sval[j] = mvv;
    ssh[j] = (mii > 360) ? (mii - 720) : mii;
  }
  for (int k = 0; k < 8; k++) {
    float best = -3.0e38f; int bj = 0;
    for (int j = 0; j < 128; j++)
      if (sval[j] > best) { best = sval[j]; bj = j; }
    int o = (((b << 7) + r) << 3) + k;
    lid[o] = bj; rv[o] = best; shf[o] = ssh[bj];
    sval[bj] = -3.0e38f;
  }
}

// ---------------------------------------------------------------- gather + DCT + bands (fp32, staged)
__global__ __launch_bounds__(256) void k_out(const float* __restrict__ x,
                                             const float* __restrict__ D,
                                             const int* __restrict__ lid,
                                             const int* __restrict__ shf,
                                             const float* __restrict__ rv,
                                             float* __restrict__ out) {
  __shared__ float Xs[9][LN];
  __shared__ float pool[9216];   // phase1/2: xe[9*720]; phase3: obuf[256*36]
  __shared__ int s_lid[8], s_shf[8];
  __shared__ float s_r[8];
  int b = blockIdx.x >> 7, c = blockIdx.x & 127;
  int t = threadIdx.x;
  if (t < 8) {
    int q = (((b << 7) + c) << 3) + t;
    s_lid[t] = lid[q]; s_shf[t] = shf[q]; s_r[t] = rv[q];
  }
  float* xe = pool;
  for (int l = t; l < LN; l += 256) xe[l] = x[(b * LN + l) * CCH + c];
  __syncthreads();
  for (int p = 1; p <= 8; p++) {
    float r = s_r[p - 1];
    if (fabsf(r) < 0.1f) {
      for (int l = t; l < LN; l += 256) xe[p * LN + l] = xe[l];
    } else {
      float sg = (r < 0.f) ? -1.f : 1.f;
      int ld = s_lid[p - 1], sh = s_shf[p - 1];
      for (int l = t; l < LN; l += 256) {
        int tt = l - sh; tt = tt < 0 ? 0 : (tt > 719 ? 719 : tt);
        xe[p * LN + l] = sg * x[(b * LN + tt) * CCH + ld];
      }
    }
  }
  __syncthreads();

  // Phase 2: X[p,k] = sum_l D[k,l]*xe[p,l]
  {
    int k0 = t, k1 = t + 256, k2 = t + 512;
    float a0[9], a1[9], a2[9];
#pragma unroll
    for (int p = 0; p < 9; p++) { a0[p] = 0.f; a1[p] = 0.f; a2[p] = 0.f; }
    const float* D0 = D + (size_t)k0 * LN;
    const float* D1 = D + (size_t)k1 * LN;
    const float* D2 = D + (size_t)(k2 < LN ? k2 : k0) * LN;
    for (int l = 0; l < LN; l++) {
      float xl[9];
#pragma unroll
      for (int p = 0; p < 9; p++) xl[p] = xe[p * LN + l];
      float d0 = D0[l], d1 = D1[l], d2 = D2[l];
#pragma unroll
      for (int p = 0; p < 9; p++) {
        a0[p] += d0 * xl[p];
        a1[p] += d1 * xl[p];
        a2[p] += d2 * xl[p];
      }
    }
#pragma unroll
    for (int p = 0; p < 9; p++) {
      Xs[p][k0] = a0[p];
      Xs[p][k1] = a1[p];
      if (k2 < LN) Xs[p][k2] = a2[p];
    }
  }
  __syncthreads();

  // Phase 3: bands, chunked over n for coalesced output
  float* obuf = pool;
  size_t outbase = (size_t)((b << 7) + c) * (LN * 36);
  for (int n0 = 0; n0 < LN; n0 += 256) {
    int nt = t & 63;
    int f = t >> 6;
    int nloc = nt * 4;
    int nchunk = (LN - n0 < 256) ? (LN - n0) : 256;
    bool act = (nloc < nchunk);
    float a[36];
#pragma unroll
    for (int q = 0; q < 36; q++) a[q] = 0.f;
    if (act) {
      const float* Dp = D + (size_t)(f * 180) * LN + (n0 + nloc);
      for (int k = 0; k < 180; k++) {
        float4 d = *(const float4*)Dp;
        Dp += LN;
        int kk = f * 180 + k;
#pragma unroll
        for (int p = 0; p < 9; p++) {
          float xv = Xs[p][kk];
          a[p * 4 + 0] += d.x * xv;
          a[p * 4 + 1] += d.y * xv;
          a[p * 4 + 2] += d.z * xv;
          a[p * 4 + 3] += d.w * xv;
        }
      }
#pragma unroll
      for (int p = 0; p < 9; p++)
#pragma unroll
        for (int nn = 0; nn < 4; nn++)
          obuf[(nloc + nn) * 36 + p * 4 + f] = a[p * 4 + nn];
    }
    __syncthreads();
    int tot = nchunk * 36;
    for (int idx = t; idx < tot; idx += 256)
      out[outbase + (size_t)n0 * 36 + idx] = obuf[idx];
    __syncthreads();
  }
}

// ---------------------------------------------------------------- launch
extern "C" void kernel_launch(void* const* d_in, const int* in_sizes, int n_in,
                              void* d_out, int out_size, void* d_ws, size_t ws_size,
                              hipStream_t stream) {
  const float* x = (const float*)d_in[0];
  float* out = (float*)d_out;

  char* ws = (char*)d_ws;
  double* ct  = (double*)ws;                      // 720
  double* st  = ct + 720;                         // 720
  double* Cm  = st + 720;                         // 361*720
  double* Sm  = Cm + NBIN * LN;                   // 361*720
  float*  nRr = (float*)(Sm + NBIN * LN);         // 1024*361
  float*  nIr = nRr + 1024 * NBIN;                // 1024*361
  float*  Mv  = nIr + 1024 * NBIN;                // 8*128*128
  float*  rv  = Mv + 8 * 128 * 128;               // 8*128*8
  float*  D   = rv + 8 * 128 * 8;                 // 720*720 (16B-aligned)
  int*    Mi  = (int*)(D + 720 * 720);            // 8*128*128
  int*    lid = Mi + 8 * 128 * 128;               // 8*128*8
  int*    shf = lid + 8 * 128 * 8;                // 8*128*8
  int2*   ptab = (int2*)(shf + 8 * 128 * 8);      // 8128

  k_twiddle<<<3, 256, 0, stream>>>(ct, st);
  k_wmat<<<(NBIN * LN + 255) / 256, 256, 0, stream>>>(ct, st, Cm, Sm);
  k_ptab<<<(NPAIRS + 255) / 256, 256, 0, stream>>>(ptab);
  k_dctmat<<<(720 * 720 + 255) / 256, 256, 0, stream>>>(D);
  k_rfft<<<8 * 128, 256, 0, stream>>>(x, ct, st, nRr, nIr);
  k_pc<<<8 * NPG, 256, 0, stream>>>(nRr, nIr, Cm, Sm, ptab, Mv, Mi);
  k_topk<<<8 * 128, 64, 0, stream>>>(Mv, Mi, lid, shf, rv);
  k_out<<<8 * 128, 256, 0, stream>>>(x, D, lid, shf, rv, out);
}